// Round 9
// baseline (171.372 us; speedup 1.0000x reference)
//
#include <hip/hip_runtime.h>
#include <math.h>

#define B 8
#define C 32
#define H 384
#define W 384
#define HW (H*W)

typedef float f4 __attribute__((ext_vector_type(4)));
typedef float f2 __attribute__((ext_vector_type(2)));

// tanh via fast exp; offsets only shift sample coords, error negligible.
__device__ __forceinline__ float fast_tanh(float v) {
    float t = __expf(2.0f * v);
    return 1.0f - 2.0f / (t + 1.0f);
}

// Reflection over [-0.5, size-0.5] then clip. Drift |ix - w| <= 1.503 =>
// xr < 2*size, one fold suffices.
__device__ __forceinline__ float reflect_fast(float coord, float span) {
    float xr = fabsf(coord + 0.5f);
    float out = (xr < span) ? (xr - 0.5f) : (2.0f * span - xr - 0.5f);
    return fminf(fmaxf(out, 0.0f), span - 1.0f);
}

// ================= offset kernel (v7, unchanged) =================
#define K1R 18
#define K1S 72
#define K1_SLOTS (K1R * 18)      // 324 f4 slots per plane

__global__ __launch_bounds__(256) void offset_kernel(
        const float* __restrict__ x,
        const float* __restrict__ ow,
        const float* __restrict__ ob,
        float2* __restrict__ ws) {
    __shared__ float xs[2][2][K1R * K1S];   // [buf][ch-in-pair] = 20736 B

    const int tid = threadIdx.x;
    const int b_ = blockIdx.z;
    const int h0 = blockIdx.y * 16;
    const int w0 = blockIdx.x * 64;
    const float* xb = x + (size_t)b_ * C * HW;

    int  goff[2], loff[2];
    bool gok[2], slot[2];
    #pragma unroll
    for (int k = 0; k < 2; ++k) {
        int idx = tid + k * 256;
        slot[k] = (idx < K1_SLOTS);
        int row = idx / 18, k4 = idx - row * 18;
        int grow = h0 - 1 + row;
        int gcol = w0 - 4 + k4 * 4;
        gok[k] = slot[k] && grow >= 0 && grow < H && gcol >= 0 && (gcol + 3) < W;
        goff[k] = max(grow, 0) * W + max(gcol, 0);
        loff[k] = row * K1S + k4 * 4;
    }

#define K1_LOADP(PF, p) do {                                             \
        const float* x0_ = xb + (size_t)(2 * (p)) * HW;                  \
        _Pragma("unroll")                                                \
        for (int k = 0; k < 2; ++k) {                                    \
            PF[k][0] = gok[k] ? *(const f4*)(x0_ + goff[k]) : (f4)0.0f;  \
            PF[k][1] = gok[k] ? *(const f4*)(x0_ + HW + goff[k]) : (f4)0.0f; \
        }                                                                \
    } while (0)
#define K1_WRITEP(bufi, PF) do {                                         \
        _Pragma("unroll")                                                \
        for (int k = 0; k < 2; ++k)                                      \
            if (slot[k]) {                                               \
                *(f4*)&xs[bufi][0][loff[k]] = PF[k][0];                  \
                *(f4*)&xs[bufi][1][loff[k]] = PF[k][1];                  \
            }                                                            \
    } while (0)

    const int tx4 = (tid & 15) * 4;
    const int ty  = tid >> 4;

    float acc0[4], acc1[4];
    {
        float b0 = ob[0], b1 = ob[1];
        #pragma unroll
        for (int q = 0; q < 4; ++q) { acc0[q] = b0; acc1[q] = b1; }
    }

#define K1_CONV(bufp, wf0, wf1) do {                                     \
        _Pragma("unroll")                                                \
        for (int ky = 0; ky < 3; ++ky) {                                 \
            int base = (ty + ky) * K1S + tx4;                            \
            f4 A = *(const f4*)&(bufp)[base];                            \
            f4 Bv = *(const f4*)&(bufp)[base + 4];                       \
            float Cv = (bufp)[base + 8];                                 \
            float in[6] = {A.w, Bv.x, Bv.y, Bv.z, Bv.w, Cv};             \
            _Pragma("unroll")                                            \
            for (int q = 0; q < 4; ++q) {                                \
                acc0[q] = fmaf(in[q], wf0[ky*3+0], fmaf(in[q+1], wf0[ky*3+1], fmaf(in[q+2], wf0[ky*3+2], acc0[q]))); \
                acc1[q] = fmaf(in[q], wf1[ky*3+0], fmaf(in[q+1], wf1[ky*3+1], fmaf(in[q+2], wf1[ky*3+2], acc1[q]))); \
            }                                                            \
        }                                                                \
    } while (0)

    f4 pf[2][2], pfN[2][2];
    K1_LOADP(pf, 0);
    K1_WRITEP(0, pf);
    __syncthreads();

    for (int p = 0; p < 16; ++p) {
        if (p + 1 < 16) K1_LOADP(pfN, p + 1);

        const int ca = 2 * p, cb = 2 * p + 1;
        const float* wa0p = ow + ca * 9;
        const float* wa1p = ow + (C + ca) * 9;
        const float* wb0p = ow + cb * 9;
        const float* wb1p = ow + (C + cb) * 9;
        float wa0[9], wa1[9], wb0[9], wb1[9];
        #pragma unroll
        for (int k = 0; k < 9; ++k) {
            wa0[k] = wa0p[k]; wa1[k] = wa1p[k];
            wb0[k] = wb0p[k]; wb1[k] = wb1p[k];
        }

        const float* bufa = xs[p & 1][0];
        const float* bufb = xs[p & 1][1];
        K1_CONV(bufa, wa0, wa1);
        K1_CONV(bufb, wb0, wb1);

        if (p + 1 < 16) K1_WRITEP((p + 1) & 1, pfN);
        __syncthreads();
    }

    const float sx = (float)W / (float)(W - 1);
    const float sy = (float)H / (float)(H - 1);
    const int hh = h0 + ty;
    float ixr[4], iyr[4];
    #pragma unroll
    for (int q = 0; q < 4; ++q) {
        float fx = (float)(w0 + tx4 + q) + fast_tanh(acc0[q]);
        float fy = (float)hh + fast_tanh(acc1[q]);
        ixr[q] = reflect_fast(fx * sx - 0.5f, (float)W);
        iyr[q] = reflect_fast(fy * sy - 0.5f, (float)H);
    }
    f4* p = (f4*)(ws + (size_t)b_ * HW + (size_t)hh * W + (w0 + tx4));
    f4 o0 = {ixr[0], iyr[0], ixr[1], iyr[1]};
    f4 o1 = {ixr[2], iyr[2], ixr[3], iyr[3]};
    p[0] = o0;
    p[1] = o1;
}

// ================= sample + depthwise conv (v9: wave-private, 0 barriers) =================
// Each wave owns 4 channels of the 64x16 tile with PRIVATE xt/xd slices.
// All dependencies (stage->sample->conv) are intra-wave: hardware lgkmcnt +
// wave-level instruction order; no __syncthreads anywhere. Meta is
// recomputed per channel from global coords (L2-hot, lane=col so decode is
// ~free: row index is scalar per loop iter, col = lane). Register prefetch
// of channel ch+1 overlaps all of channel ch.
#define NC 16
#define XTR 22
#define XTS 72
#define XT_SLOTS (XTR * 18)     // 396 f4 slots; NOTE 72 = 18*4 -> linear: addr = 4*idx
#define XDS 68

__global__ __launch_bounds__(256, 3) void sample_dw_kernel(
        const float* __restrict__ x,
        const float2* __restrict__ ws,
        const float* __restrict__ dww,
        float* __restrict__ out) {
    __shared__ float xt[4][XTR * XTS];   // 4 x 6336 B
    __shared__ float xd[4][18 * XDS];    // 4 x 4896 B  (total 44928 B -> 3 blocks/CU)

    const int tid = threadIdx.x;
    const int wv  = tid >> 6;
    const int ln  = tid & 63;
    const int bz  = blockIdx.z;          // b*2 + cg
    const int b_  = bz >> 1;
    const int c0  = (bz & 1) * NC + wv * 4;   // this wave's first channel
    const int h0  = blockIdx.y * 16;
    const int w0  = blockIdx.x * 64;

    const float* xb = x + ((size_t)b_ * C + c0) * HW;
    const float2* wsb = ws + (size_t)b_ * HW;

    // channel-invariant staging descriptors (clamped; clamped garbage is
    // only ever read by taps of in-image pixels, which stay in-window)
    int sg[7], sl[7];
    bool sv[7];
    #pragma unroll
    for (int k = 0; k < 7; ++k) {
        int idx = k * 64 + ln;
        sv[k] = (idx < XT_SLOTS);
        int row = idx / 18, k4 = idx - row * 18;
        int grow = min(max(h0 - 3 + row, 0), H - 1);
        int gcol = min(max(w0 - 4 + k4 * 4, 0), W - 4);
        sg[k] = grow * W + gcol;
        sl[k] = idx * 4;                  // stride 72 == 18 f4 -> linear layout
    }

    float* xtw = xt[wv];
    float* xdw = xd[wv];

    const int  wp    = w0 - 1 + ln;       // sampled pixel column (main rows)
    const bool colok = (wp >= 0) && (wp < W);
    const int  wpc   = min(max(wp, 0), W - 1);
    const int  addr_base = (h0 - 3) * XTS + (w0 - 4);

    f4 pf[7];
    #pragma unroll
    for (int k = 0; k < 7; ++k)
        if (sv[k]) pf[k] = *(const f4*)(xb + sg[k]);

    for (int ch = 0; ch < 4; ++ch) {
        // stage regs -> private xt (vmcnt wait inserted by compiler)
        #pragma unroll
        for (int k = 0; k < 7; ++k)
            if (sv[k]) *(f4*)&xtw[sl[k]] = pf[k];

        // prefetch next channel; overlaps everything below
        if (ch < 3) {
            const float* xc = xb + (size_t)(ch + 1) * HW;
            #pragma unroll
            for (int k = 0; k < 7; ++k)
                if (sv[k]) pf[k] = *(const f4*)(xc + sg[k]);
        }

        // sample main rows: row = s (scalar), col = lane
        #pragma unroll 3
        for (int s = 0; s < 18; ++s) {
            int hp = h0 - 1 + s;
            float v = 0.0f;
            if (hp >= 0 && hp < H) {              // wave-uniform branch
                float2 crd = wsb[hp * W + wpc];
                float ix0f = floorf(crd.x), iy0f = floorf(crd.y);
                float wx1 = crd.x - ix0f, wy1 = crd.y - iy0f;
                float wx0 = 1.0f - wx1, wy0 = 1.0f - wy1;
                int ix0 = min(max((int)ix0f, 0), W - 1);
                int iy0 = min(max((int)iy0f, 0), H - 1);
                int a = iy0 * XTS + ix0 - addr_base;
                float v00 = xtw[a],       v01 = xtw[a + 1];
                float v10 = xtw[a + XTS], v11 = xtw[a + XTS + 1];
                v = (v00 * wx0 + v01 * wx1) * wy0 + (v10 * wx0 + v11 * wx1) * wy1;
                v = colok ? v : 0.0f;
            }
            xdw[s * XDS + ln] = v;
        }
        // 36 edge samples (xd cols 64,65)
        if (ln < 36) {
            int r = ln >> 1, q = 64 + (ln & 1);
            int hp = h0 - 1 + r;
            int wpe = w0 - 1 + q;
            float v = 0.0f;
            if (hp >= 0 && hp < H && wpe < W) {
                float2 crd = wsb[hp * W + wpe];
                float ix0f = floorf(crd.x), iy0f = floorf(crd.y);
                float wx1 = crd.x - ix0f, wy1 = crd.y - iy0f;
                float wx0 = 1.0f - wx1, wy0 = 1.0f - wy1;
                int ix0 = min(max((int)ix0f, 0), W - 1);
                int iy0 = min(max((int)iy0f, 0), H - 1);
                int a = iy0 * XTS + ix0 - addr_base;
                float v00 = xtw[a],       v01 = xtw[a + 1];
                float v10 = xtw[a + XTS], v11 = xtw[a + XTS + 1];
                v = (v00 * wx0 + v01 * wx1) * wy0 + (v10 * wx0 + v11 * wx1) * wy1;
            }
            xdw[r * XDS + q] = v;
        }

        // depthwise weights (wave-uniform -> scalar loads)
        float wk[9];
        const float* wc = dww + (size_t)(c0 + ch) * 9;
        #pragma unroll
        for (int i = 0; i < 9; ++i) wk[i] = wc[i];

        // conv: 4x4 outputs per lane from private xd (same-wave LDS order)
        const int r0 = 4 * (ln >> 4);
        const int cq = 4 * (ln & 15);
        float rw[6][6];
        #pragma unroll
        for (int rr = 0; rr < 6; ++rr) {
            int base = (r0 + rr) * XDS + cq;
            f2 p0 = *(const f2*)&xdw[base];
            f2 p1 = *(const f2*)&xdw[base + 2];
            f2 p2 = *(const f2*)&xdw[base + 4];
            rw[rr][0] = p0.x; rw[rr][1] = p0.y; rw[rr][2] = p1.x;
            rw[rr][3] = p1.y; rw[rr][4] = p2.x; rw[rr][5] = p2.y;
        }
        float* outc = out + ((size_t)b_ * C + c0 + ch) * HW;
        #pragma unroll
        for (int j = 0; j < 4; ++j) {
            float a4[4] = {0.f, 0.f, 0.f, 0.f};
            #pragma unroll
            for (int ky = 0; ky < 3; ++ky)
                #pragma unroll
                for (int q = 0; q < 4; ++q)
                    a4[q] = fmaf(rw[j+ky][q],   wk[ky*3+0],
                            fmaf(rw[j+ky][q+1], wk[ky*3+1],
                            fmaf(rw[j+ky][q+2], wk[ky*3+2], a4[q])));
            f4 res = {fmaxf(a4[0], 0.f), fmaxf(a4[1], 0.f),
                      fmaxf(a4[2], 0.f), fmaxf(a4[3], 0.f)};
            float* op = outc + (size_t)(h0 + r0 + j) * W + (w0 + cq);
            __builtin_nontemporal_store(res, (f4*)op);
        }
        // next iteration overwrites xtw/xdw: same-wave program order is the fence
    }
}

extern "C" void kernel_launch(void* const* d_in, const int* in_sizes, int n_in,
                              void* d_out, int out_size, void* d_ws, size_t ws_size,
                              hipStream_t stream) {
    const float* x   = (const float*)d_in[0];
    const float* ow  = (const float*)d_in[1];
    const float* ob  = (const float*)d_in[2];
    const float* dww = (const float*)d_in[3];
    float* out = (float*)d_out;
    float2* ws = (float2*)d_ws;

    dim3 g1(W / 64, H / 16, B);
    offset_kernel<<<g1, 256, 0, stream>>>(x, ow, ob, ws);

    dim3 g2(W / 64, H / 16, B * (C / NC));
    sample_dw_kernel<<<g2, 256, 0, stream>>>(x, ws, dww, out);
}

// Round 10
// 140.542 us; speedup vs baseline: 1.2194x; 1.2194x over previous
//
#include <hip/hip_runtime.h>
#include <math.h>

#define B 8
#define C 32
#define H 384
#define W 384
#define HW (H*W)

typedef float f4 __attribute__((ext_vector_type(4)));
typedef float f2 __attribute__((ext_vector_type(2)));

// tanh via fast exp; offsets only shift sample coords, error negligible.
__device__ __forceinline__ float fast_tanh(float v) {
    float t = __expf(2.0f * v);
    return 1.0f - 2.0f / (t + 1.0f);
}

// Reflection over [-0.5, size-0.5] then clip. Drift |ix - w| <= 1.503 =>
// xr < 2*size, one fold suffices.
__device__ __forceinline__ float reflect_fast(float coord, float span) {
    float xr = fabsf(coord + 0.5f);
    float out = (xr < span) ? (xr - 0.5f) : (2.0f * span - xr - 0.5f);
    return fminf(fmaxf(out, 0.0f), span - 1.0f);
}

// ================= offset kernel (v8: 32x16 tile, 2304 blocks) =================
// K1 was grid-starved (1152 blocks = 4.5/CU, latency-bound at 70% stall).
// 32x16 tile doubles the grid to 9 blocks/CU. Stage rows [h0-1,h0+17) x
// cols [w0-4,w0+36) zero-padded; channel-pair double-buffer, 1 barrier/pair.
// Conv: 1 col x 2 rows per thread, 12 scalar b32 LDS reads per plane
// (consecutive-lane addrs -> 2 lanes/bank = conflict-free).
#define K1R 18
#define K1CS 40
#define K1_SLOTS (K1R * 10)      // 180 f4 slots per plane

__global__ __launch_bounds__(256) void offset_kernel(
        const float* __restrict__ x,
        const float* __restrict__ ow,
        const float* __restrict__ ob,
        float2* __restrict__ ws) {
    __shared__ float xs[2][2][K1R * K1CS];   // [buf][ch-in-pair] = 11520 B

    const int tid = threadIdx.x;
    const int b_ = blockIdx.z;
    const int h0 = blockIdx.y * 16;
    const int w0 = blockIdx.x * 32;
    const float* xb = x + (size_t)b_ * C * HW;

    // channel-invariant staging descriptors (zero-pad)
    const bool slot = (tid < K1_SLOTS);
    int goff = 0, loff = 0;
    bool gok = false;
    {
        int row = tid / 10, k4 = tid - row * 10;
        int grow = h0 - 1 + row;
        int gcol = w0 - 4 + k4 * 4;
        gok = slot && grow >= 0 && grow < H && gcol >= 0 && (gcol + 3) < W;
        goff = max(grow, 0) * W + max(gcol, 0);
        loff = row * K1CS + k4 * 4;
    }

#define K1_LOADP(PF, p) do {                                             \
        const float* x0_ = xb + (size_t)(2 * (p)) * HW;                  \
        PF[0] = gok ? *(const f4*)(x0_ + goff) : (f4)0.0f;               \
        PF[1] = gok ? *(const f4*)(x0_ + HW + goff) : (f4)0.0f;          \
    } while (0)
#define K1_WRITEP(bufi, PF) do {                                         \
        if (slot) {                                                      \
            *(f4*)&xs[bufi][0][loff] = PF[0];                            \
            *(f4*)&xs[bufi][1][loff] = PF[1];                            \
        }                                                                \
    } while (0)

    const int tx  = tid & 31;          // output col
    const int typ = (tid >> 5) * 2;    // output rows typ, typ+1

    float acc0[2], acc1[2];
    {
        float b0 = ob[0], b1 = ob[1];
        acc0[0] = b0; acc0[1] = b0;
        acc1[0] = b1; acc1[1] = b1;
    }

    // conv over one staged plane for channel ca (both output filters)
#define K1_CONV(bufp, ca) do {                                           \
        float wf0[9], wf1[9];                                            \
        const float* w0p_ = ow + (ca) * 9;                               \
        const float* w1p_ = ow + (C + (ca)) * 9;                         \
        _Pragma("unroll")                                                \
        for (int k = 0; k < 9; ++k) { wf0[k] = w0p_[k]; wf1[k] = w1p_[k]; } \
        float in[4][3];                                                  \
        _Pragma("unroll")                                                \
        for (int rr = 0; rr < 4; ++rr) {                                 \
            int base = (typ + rr) * K1CS + tx + 3;                       \
            in[rr][0] = (bufp)[base];                                    \
            in[rr][1] = (bufp)[base + 1];                                \
            in[rr][2] = (bufp)[base + 2];                                \
        }                                                                \
        _Pragma("unroll")                                                \
        for (int j = 0; j < 2; ++j)                                      \
            _Pragma("unroll")                                            \
            for (int ky = 0; ky < 3; ++ky)                               \
                _Pragma("unroll")                                        \
                for (int kx = 0; kx < 3; ++kx) {                         \
                    acc0[j] = fmaf(in[j + ky][kx], wf0[ky*3+kx], acc0[j]); \
                    acc1[j] = fmaf(in[j + ky][kx], wf1[ky*3+kx], acc1[j]); \
                }                                                        \
    } while (0)

    f4 pf[2], pfN[2];
    K1_LOADP(pf, 0);
    K1_WRITEP(0, pf);
    __syncthreads();

    for (int p = 0; p < 16; ++p) {
        if (p + 1 < 16) K1_LOADP(pfN, p + 1);

        const float* bufa = xs[p & 1][0];
        const float* bufb = xs[p & 1][1];
        K1_CONV(bufa, 2 * p);
        K1_CONV(bufb, 2 * p + 1);

        if (p + 1 < 16) K1_WRITEP((p + 1) & 1, pfN);
        __syncthreads();
    }

    // tanh -> abs coords -> reflect -> store (ix,iy) pairs
    const float sx = (float)W / (float)(W - 1);
    const float sy = (float)H / (float)(H - 1);
    #pragma unroll
    for (int j = 0; j < 2; ++j) {
        int hh = h0 + typ + j;
        float fx = (float)(w0 + tx) + fast_tanh(acc0[j]);
        float fy = (float)hh + fast_tanh(acc1[j]);
        float2 o;
        o.x = reflect_fast(fx * sx - 0.5f, (float)W);
        o.y = reflect_fast(fy * sy - 0.5f, (float)H);
        ws[(size_t)b_ * HW + (size_t)hh * W + (w0 + tx)] = o;
    }
}

// ================= sample + depthwise conv (v10 = R4-best + nt + XCD swizzle) =================
// R4's measured-best structure (85us): 64x16 tile, NC=8, meta in LDS,
// single xt buffer, 3 barriers/channel, 1-ahead register prefetch.
// Deltas: nontemporal out stores; flattened grid with bijective XCD-chunked
// swizzle (4608 % 8 == 0) for halo/coord L2 locality.
#define NC 8
#define XT_ROWS 22
#define XT_STRIDE 72
#define XT_N (XT_ROWS * XT_STRIDE)          // 1584 floats
#define XT_LOADS (XT_ROWS * 18)             // 396 float4 loads
#define XD_ROWS 18
#define XD_COLS 66
#define XD_STRIDE 68
#define META_N (XD_ROWS * XD_COLS)          // 1188
#define K2_GX 6
#define K2_GY 24
#define K2_GZ (B * (C / NC))                // 32
#define K2_NWG (K2_GX * K2_GY * K2_GZ)      // 4608
#define K2_CPX (K2_NWG / 8)                 // 576

__global__ __launch_bounds__(256) void sample_dw_kernel(
        const float* __restrict__ x,
        const float2* __restrict__ ws,
        const float* __restrict__ dww,
        float* __restrict__ out) {
    __shared__ float xt[XT_N];
    __shared__ float xd[XD_ROWS * XD_STRIDE];
    __shared__ unsigned int m_addr[META_N];
    __shared__ float m_wx[META_N];
    __shared__ float m_wy[META_N];

    const int tid = threadIdx.x;
    // XCD-chunked bijective swizzle of the flat workgroup id
    const int id = blockIdx.x;
    const int nid = (id & 7) * K2_CPX + (id >> 3);
    const int bz = nid / (K2_GX * K2_GY);
    const int rem = nid - bz * (K2_GX * K2_GY);
    const int by = rem / K2_GX;
    const int bx = rem - by * K2_GX;

    const int b_ = bz >> 2;
    const int c0 = (bz & 3) * NC;
    const int h0 = by * 16;
    const int w0 = bx * 64;

    const float* xb = x + ((size_t)b_ * C + c0) * HW;
    const float2* wsb = ws + (size_t)b_ * HW;

    // prefetch channel 0 x-tile into regs
    f4 pf[2];
    #pragma unroll
    for (int k = 0; k < 2; ++k) {
        int idx = tid + k * 256;
        f4 v = (f4)0.0f;
        if (idx < XT_LOADS) {
            int row = idx / 18, k4 = idx % 18;
            int grow = min(max(h0 - 3 + row, 0), H - 1);
            int gcol = min(max(w0 - 4 + k4 * 4, 0), W - 4);
            v = *(const f4*)(xb + grow * W + gcol);
        }
        pf[k] = v;
    }

    // Phase A: per-pixel meta, shared across channels
    const int addr_base = (h0 - 3) * XT_STRIDE + (w0 - 4);
    #pragma unroll
    for (int k = 0; k < 5; ++k) {
        int i = tid + k * 256;
        if (i < META_N) {
            int r = i / XD_COLS, q = i - r * XD_COLS;
            int hp = h0 - 1 + r, wp = w0 - 1 + q;
            unsigned int addr = 0xFFFFFFFFu;
            float wx1 = 0.f, wy1 = 0.f;
            if (hp >= 0 && hp < H && wp >= 0 && wp < W) {
                float2 crd = wsb[hp * W + wp];
                float ix0f = floorf(crd.x), iy0f = floorf(crd.y);
                wx1 = crd.x - ix0f; wy1 = crd.y - iy0f;
                int ix0 = min(max((int)ix0f, 0), W - 1);
                int iy0 = min(max((int)iy0f, 0), H - 1);
                addr = (unsigned int)(iy0 * XT_STRIDE + ix0 - addr_base);
            }
            m_addr[i] = addr;
            m_wx[i] = wx1;
            m_wy[i] = wy1;
        }
    }
    __syncthreads();

    for (int cc = 0; cc < NC; ++cc) {
        // write staged x-tile regs -> LDS
        #pragma unroll
        for (int k = 0; k < 2; ++k) {
            int idx = tid + k * 256;
            if (idx < XT_LOADS) {
                int row = idx / 18, k4 = idx % 18;
                *(f4*)&xt[row * XT_STRIDE + k4 * 4] = pf[k];
            }
        }
        __syncthreads();

        // prefetch next channel (hides under sample+conv)
        if (cc + 1 < NC) {
            const float* xc = xb + (size_t)(cc + 1) * HW;
            #pragma unroll
            for (int k = 0; k < 2; ++k) {
                int idx = tid + k * 256;
                f4 v = (f4)0.0f;
                if (idx < XT_LOADS) {
                    int row = idx / 18, k4 = idx % 18;
                    int grow = min(max(h0 - 3 + row, 0), H - 1);
                    int gcol = min(max(w0 - 4 + k4 * 4, 0), W - 4);
                    v = *(const f4*)(xc + grow * W + gcol);
                }
                pf[k] = v;
            }
        }

        // sample from xt -> xd
        #pragma unroll
        for (int k = 0; k < 5; ++k) {
            int i = tid + k * 256;
            if (i < META_N) {
                int r = i / XD_COLS, q = i - r * XD_COLS;
                unsigned int addr = m_addr[i];
                float v = 0.0f;
                if (addr != 0xFFFFFFFFu) {
                    float wx1 = m_wx[i], wy1 = m_wy[i];
                    float wx0 = 1.0f - wx1, wy0 = 1.0f - wy1;
                    float v00 = xt[addr];
                    float v01 = xt[addr + 1];
                    float v10 = xt[addr + XT_STRIDE];
                    float v11 = xt[addr + XT_STRIDE + 1];
                    v = (v00 * wx0 + v01 * wx1) * wy0 + (v10 * wx0 + v11 * wx1) * wy1;
                }
                xd[r * XD_STRIDE + q] = v;
            }
        }

        // depthwise weights (wave-uniform -> scalar loads)
        float wk[9];
        const float* wc = dww + (size_t)(c0 + cc) * 9;
        #pragma unroll
        for (int i = 0; i < 9; ++i) wk[i] = wc[i];

        __syncthreads();

        // 3x3 depthwise conv from xd + ReLU; 2x2 outputs per thread
        const int tx2 = (tid & 31) * 2;
        const int ty0 = (tid >> 5) * 2;
        float a[2][2] = {{0.f, 0.f}, {0.f, 0.f}};
        #pragma unroll
        for (int r = 0; r < 4; ++r) {
            const float* rowp = xd + (ty0 + r) * XD_STRIDE + tx2;
            f2 p0 = *(const f2*)rowp;
            f2 p1 = *(const f2*)(rowp + 2);
            #pragma unroll
            for (int ky = 0; ky < 3; ++ky) {
                int j = r - ky;
                if (j < 0 || j > 1) continue;
                a[j][0] = fmaf(p0.x, wk[ky*3+0], fmaf(p0.y, wk[ky*3+1], fmaf(p1.x, wk[ky*3+2], a[j][0])));
                a[j][1] = fmaf(p0.y, wk[ky*3+0], fmaf(p1.x, wk[ky*3+1], fmaf(p1.y, wk[ky*3+2], a[j][1])));
            }
        }
        float* outc = out + ((size_t)b_ * C + c0 + cc) * HW;
        #pragma unroll
        for (int j = 0; j < 2; ++j) {
            f2 res;
            res.x = fmaxf(a[j][0], 0.0f);
            res.y = fmaxf(a[j][1], 0.0f);
            __builtin_nontemporal_store(res,
                (f2*)&outc[(size_t)(h0 + ty0 + j) * W + (w0 + tx2)]);
        }
        __syncthreads();
    }
}

extern "C" void kernel_launch(void* const* d_in, const int* in_sizes, int n_in,
                              void* d_out, int out_size, void* d_ws, size_t ws_size,
                              hipStream_t stream) {
    const float* x   = (const float*)d_in[0];
    const float* ow  = (const float*)d_in[1];
    const float* ob  = (const float*)d_in[2];
    const float* dww = (const float*)d_in[3];
    float* out = (float*)d_out;
    float2* ws = (float2*)d_ws;

    dim3 g1(W / 32, H / 16, B);
    offset_kernel<<<g1, 256, 0, stream>>>(x, ow, ob, ws);

    sample_dw_kernel<<<dim3(K2_NWG), 256, 0, stream>>>(x, ws, dww, out);
}

// Round 11
// 111.828 us; speedup vs baseline: 1.5325x; 1.2568x over previous
//
#include <hip/hip_runtime.h>
#include <math.h>

#define B 8
#define C 32
#define H 384
#define W 384
#define HW (H*W)

typedef float f4 __attribute__((ext_vector_type(4)));
typedef float f2 __attribute__((ext_vector_type(2)));

// tanh via fast exp; offsets only shift sample coords, error negligible.
__device__ __forceinline__ float fast_tanh(float v) {
    float t = __expf(2.0f * v);
    return 1.0f - 2.0f / (t + 1.0f);
}

// Reflection over [-0.5, size-0.5] then clip. Drift |ix - w| <= 1.503 =>
// xr < 2*size, one fold suffices.
__device__ __forceinline__ float reflect_fast(float coord, float span) {
    float xr = fabsf(coord + 0.5f);
    float out = (xr < span) ? (xr - 0.5f) : (2.0f * span - xr - 0.5f);
    return fminf(fmaxf(out, 0.0f), span - 1.0f);
}

// ================= offset kernel (v7: 64x16, channel-pair dbuf; ~48.5us in R8) =================
#define K1R 18
#define K1S 72
#define K1_SLOTS (K1R * 18)      // 324 f4 slots per plane

__global__ __launch_bounds__(256) void offset_kernel(
        const float* __restrict__ x,
        const float* __restrict__ ow,
        const float* __restrict__ ob,
        float2* __restrict__ ws) {
    __shared__ float xs[2][2][K1R * K1S];   // [buf][ch-in-pair] = 20736 B

    const int tid = threadIdx.x;
    const int b_ = blockIdx.z;
    const int h0 = blockIdx.y * 16;
    const int w0 = blockIdx.x * 64;
    const float* xb = x + (size_t)b_ * C * HW;

    int  goff[2], loff[2];
    bool gok[2], slot[2];
    #pragma unroll
    for (int k = 0; k < 2; ++k) {
        int idx = tid + k * 256;
        slot[k] = (idx < K1_SLOTS);
        int row = idx / 18, k4 = idx - row * 18;
        int grow = h0 - 1 + row;
        int gcol = w0 - 4 + k4 * 4;
        gok[k] = slot[k] && grow >= 0 && grow < H && gcol >= 0 && (gcol + 3) < W;
        goff[k] = max(grow, 0) * W + max(gcol, 0);
        loff[k] = row * K1S + k4 * 4;
    }

#define K1_LOADP(PF, p) do {                                             \
        const float* x0_ = xb + (size_t)(2 * (p)) * HW;                  \
        _Pragma("unroll")                                                \
        for (int k = 0; k < 2; ++k) {                                    \
            PF[k][0] = gok[k] ? *(const f4*)(x0_ + goff[k]) : (f4)0.0f;  \
            PF[k][1] = gok[k] ? *(const f4*)(x0_ + HW + goff[k]) : (f4)0.0f; \
        }                                                                \
    } while (0)
#define K1_WRITEP(bufi, PF) do {                                         \
        _Pragma("unroll")                                                \
        for (int k = 0; k < 2; ++k)                                      \
            if (slot[k]) {                                               \
                *(f4*)&xs[bufi][0][loff[k]] = PF[k][0];                  \
                *(f4*)&xs[bufi][1][loff[k]] = PF[k][1];                  \
            }                                                            \
    } while (0)

    const int tx4 = (tid & 15) * 4;
    const int ty  = tid >> 4;

    float acc0[4], acc1[4];
    {
        float b0 = ob[0], b1 = ob[1];
        #pragma unroll
        for (int q = 0; q < 4; ++q) { acc0[q] = b0; acc1[q] = b1; }
    }

#define K1_CONV(bufp, wf0, wf1) do {                                     \
        _Pragma("unroll")                                                \
        for (int ky = 0; ky < 3; ++ky) {                                 \
            int base = (ty + ky) * K1S + tx4;                            \
            f4 A = *(const f4*)&(bufp)[base];                            \
            f4 Bv = *(const f4*)&(bufp)[base + 4];                       \
            float Cv = (bufp)[base + 8];                                 \
            float in[6] = {A.w, Bv.x, Bv.y, Bv.z, Bv.w, Cv};             \
            _Pragma("unroll")                                            \
            for (int q = 0; q < 4; ++q) {                                \
                acc0[q] = fmaf(in[q], wf0[ky*3+0], fmaf(in[q+1], wf0[ky*3+1], fmaf(in[q+2], wf0[ky*3+2], acc0[q]))); \
                acc1[q] = fmaf(in[q], wf1[ky*3+0], fmaf(in[q+1], wf1[ky*3+1], fmaf(in[q+2], wf1[ky*3+2], acc1[q]))); \
            }                                                            \
        }                                                                \
    } while (0)

    f4 pf[2][2], pfN[2][2];
    K1_LOADP(pf, 0);
    K1_WRITEP(0, pf);
    __syncthreads();

    for (int p = 0; p < 16; ++p) {
        if (p + 1 < 16) K1_LOADP(pfN, p + 1);

        const int ca = 2 * p, cb = 2 * p + 1;
        const float* wa0p = ow + ca * 9;
        const float* wa1p = ow + (C + ca) * 9;
        const float* wb0p = ow + cb * 9;
        const float* wb1p = ow + (C + cb) * 9;
        float wa0[9], wa1[9], wb0[9], wb1[9];
        #pragma unroll
        for (int k = 0; k < 9; ++k) {
            wa0[k] = wa0p[k]; wa1[k] = wa1p[k];
            wb0[k] = wb0p[k]; wb1[k] = wb1p[k];
        }

        const float* bufa = xs[p & 1][0];
        const float* bufb = xs[p & 1][1];
        K1_CONV(bufa, wa0, wa1);
        K1_CONV(bufb, wb0, wb1);

        if (p + 1 < 16) K1_WRITEP((p + 1) & 1, pfN);
        __syncthreads();
    }

    const float sx = (float)W / (float)(W - 1);
    const float sy = (float)H / (float)(H - 1);
    const int hh = h0 + ty;
    float ixr[4], iyr[4];
    #pragma unroll
    for (int q = 0; q < 4; ++q) {
        float fx = (float)(w0 + tx4 + q) + fast_tanh(acc0[q]);
        float fy = (float)hh + fast_tanh(acc1[q]);
        ixr[q] = reflect_fast(fx * sx - 0.5f, (float)W);
        iyr[q] = reflect_fast(fy * sy - 0.5f, (float)H);
    }
    f4* p = (f4*)(ws + (size_t)b_ * HW + (size_t)hh * W + (w0 + tx4));
    f4 o0 = {ixr[0], iyr[0], ixr[1], iyr[1]};
    f4 o1 = {ixr[2], iyr[2], ixr[3], iyr[3]};
    p[0] = o0;
    p[1] = o1;
}

// ================= sample + depthwise conv (v10: R4-best + nt + XCD swizzle) =================
#define NC 8
#define XT_ROWS 22
#define XT_STRIDE 72
#define XT_N (XT_ROWS * XT_STRIDE)          // 1584 floats
#define XT_LOADS (XT_ROWS * 18)             // 396 float4 loads
#define XD_ROWS 18
#define XD_COLS 66
#define XD_STRIDE 68
#define META_N (XD_ROWS * XD_COLS)          // 1188
#define K2_GX 6
#define K2_GY 24
#define K2_GZ (B * (C / NC))                // 32
#define K2_NWG (K2_GX * K2_GY * K2_GZ)      // 4608
#define K2_CPX (K2_NWG / 8)                 // 576

__global__ __launch_bounds__(256) void sample_dw_kernel(
        const float* __restrict__ x,
        const float2* __restrict__ ws,
        const float* __restrict__ dww,
        float* __restrict__ out) {
    __shared__ float xt[XT_N];
    __shared__ float xd[XD_ROWS * XD_STRIDE];
    __shared__ unsigned int m_addr[META_N];
    __shared__ float m_wx[META_N];
    __shared__ float m_wy[META_N];

    const int tid = threadIdx.x;
    // XCD-chunked bijective swizzle of the flat workgroup id
    const int id = blockIdx.x;
    const int nid = (id & 7) * K2_CPX + (id >> 3);
    const int bz = nid / (K2_GX * K2_GY);
    const int rem = nid - bz * (K2_GX * K2_GY);
    const int by = rem / K2_GX;
    const int bx = rem - by * K2_GX;

    const int b_ = bz >> 2;
    const int c0 = (bz & 3) * NC;
    const int h0 = by * 16;
    const int w0 = bx * 64;

    const float* xb = x + ((size_t)b_ * C + c0) * HW;
    const float2* wsb = ws + (size_t)b_ * HW;

    // prefetch channel 0 x-tile into regs
    f4 pf[2];
    #pragma unroll
    for (int k = 0; k < 2; ++k) {
        int idx = tid + k * 256;
        f4 v = (f4)0.0f;
        if (idx < XT_LOADS) {
            int row = idx / 18, k4 = idx % 18;
            int grow = min(max(h0 - 3 + row, 0), H - 1);
            int gcol = min(max(w0 - 4 + k4 * 4, 0), W - 4);
            v = *(const f4*)(xb + grow * W + gcol);
        }
        pf[k] = v;
    }

    // Phase A: per-pixel meta, shared across channels
    const int addr_base = (h0 - 3) * XT_STRIDE + (w0 - 4);
    #pragma unroll
    for (int k = 0; k < 5; ++k) {
        int i = tid + k * 256;
        if (i < META_N) {
            int r = i / XD_COLS, q = i - r * XD_COLS;
            int hp = h0 - 1 + r, wp = w0 - 1 + q;
            unsigned int addr = 0xFFFFFFFFu;
            float wx1 = 0.f, wy1 = 0.f;
            if (hp >= 0 && hp < H && wp >= 0 && wp < W) {
                float2 crd = wsb[hp * W + wp];
                float ix0f = floorf(crd.x), iy0f = floorf(crd.y);
                wx1 = crd.x - ix0f; wy1 = crd.y - iy0f;
                int ix0 = min(max((int)ix0f, 0), W - 1);
                int iy0 = min(max((int)iy0f, 0), H - 1);
                addr = (unsigned int)(iy0 * XT_STRIDE + ix0 - addr_base);
            }
            m_addr[i] = addr;
            m_wx[i] = wx1;
            m_wy[i] = wy1;
        }
    }
    __syncthreads();

    for (int cc = 0; cc < NC; ++cc) {
        // write staged x-tile regs -> LDS
        #pragma unroll
        for (int k = 0; k < 2; ++k) {
            int idx = tid + k * 256;
            if (idx < XT_LOADS) {
                int row = idx / 18, k4 = idx % 18;
                *(f4*)&xt[row * XT_STRIDE + k4 * 4] = pf[k];
            }
        }
        __syncthreads();

        // prefetch next channel (hides under sample+conv)
        if (cc + 1 < NC) {
            const float* xc = xb + (size_t)(cc + 1) * HW;
            #pragma unroll
            for (int k = 0; k < 2; ++k) {
                int idx = tid + k * 256;
                f4 v = (f4)0.0f;
                if (idx < XT_LOADS) {
                    int row = idx / 18, k4 = idx % 18;
                    int grow = min(max(h0 - 3 + row, 0), H - 1);
                    int gcol = min(max(w0 - 4 + k4 * 4, 0), W - 4);
                    v = *(const f4*)(xc + grow * W + gcol);
                }
                pf[k] = v;
            }
        }

        // sample from xt -> xd
        #pragma unroll
        for (int k = 0; k < 5; ++k) {
            int i = tid + k * 256;
            if (i < META_N) {
                int r = i / XD_COLS, q = i - r * XD_COLS;
                unsigned int addr = m_addr[i];
                float v = 0.0f;
                if (addr != 0xFFFFFFFFu) {
                    float wx1 = m_wx[i], wy1 = m_wy[i];
                    float wx0 = 1.0f - wx1, wy0 = 1.0f - wy1;
                    float v00 = xt[addr];
                    float v01 = xt[addr + 1];
                    float v10 = xt[addr + XT_STRIDE];
                    float v11 = xt[addr + XT_STRIDE + 1];
                    v = (v00 * wx0 + v01 * wx1) * wy0 + (v10 * wx0 + v11 * wx1) * wy1;
                }
                xd[r * XD_STRIDE + q] = v;
            }
        }

        // depthwise weights (wave-uniform -> scalar loads)
        float wk[9];
        const float* wc = dww + (size_t)(c0 + cc) * 9;
        #pragma unroll
        for (int i = 0; i < 9; ++i) wk[i] = wc[i];

        __syncthreads();

        // 3x3 depthwise conv from xd + ReLU; 2x2 outputs per thread
        const int tx2 = (tid & 31) * 2;
        const int ty0 = (tid >> 5) * 2;
        float a[2][2] = {{0.f, 0.f}, {0.f, 0.f}};
        #pragma unroll
        for (int r = 0; r < 4; ++r) {
            const float* rowp = xd + (ty0 + r) * XD_STRIDE + tx2;
            f2 p0 = *(const f2*)rowp;
            f2 p1 = *(const f2*)(rowp + 2);
            #pragma unroll
            for (int ky = 0; ky < 3; ++ky) {
                int j = r - ky;
                if (j < 0 || j > 1) continue;
                a[j][0] = fmaf(p0.x, wk[ky*3+0], fmaf(p0.y, wk[ky*3+1], fmaf(p1.x, wk[ky*3+2], a[j][0])));
                a[j][1] = fmaf(p0.y, wk[ky*3+0], fmaf(p1.x, wk[ky*3+1], fmaf(p1.y, wk[ky*3+2], a[j][1])));
            }
        }
        float* outc = out + ((size_t)b_ * C + c0 + cc) * HW;
        #pragma unroll
        for (int j = 0; j < 2; ++j) {
            f2 res;
            res.x = fmaxf(a[j][0], 0.0f);
            res.y = fmaxf(a[j][1], 0.0f);
            __builtin_nontemporal_store(res,
                (f2*)&outc[(size_t)(h0 + ty0 + j) * W + (w0 + tx2)]);
        }
        __syncthreads();
    }
}

extern "C" void kernel_launch(void* const* d_in, const int* in_sizes, int n_in,
                              void* d_out, int out_size, void* d_ws, size_t ws_size,
                              hipStream_t stream) {
    const float* x   = (const float*)d_in[0];
    const float* ow  = (const float*)d_in[1];
    const float* ob  = (const float*)d_in[2];
    const float* dww = (const float*)d_in[3];
    float* out = (float*)d_out;
    float2* ws = (float2*)d_ws;

    dim3 g1(W / 64, H / 16, B);
    offset_kernel<<<g1, 256, 0, stream>>>(x, ow, ob, ws);

    sample_dw_kernel<<<dim3(K2_NWG), 256, 0, stream>>>(x, ws, dww, out);
}

// Round 13
// 110.063 us; speedup vs baseline: 1.5570x; 1.0160x over previous
//
#include <hip/hip_runtime.h>
#include <math.h>

#define B 8
#define C 32
#define H 384
#define W 384
#define HW (H*W)

typedef float f4 __attribute__((ext_vector_type(4)));
typedef float f2 __attribute__((ext_vector_type(2)));

// 16B of guaranteed zeros in global memory (.bss, never written) — the
// global-source target for out-of-image staging granules of gload_lds.
__device__ __attribute__((aligned(16))) float ZERO_TILE[4];

__device__ __forceinline__ void gl_lds16(const float* gsrc, float* lds_dst) {
    __builtin_amdgcn_global_load_lds(
        (const __attribute__((address_space(1))) void*)gsrc,
        (__attribute__((address_space(3))) void*)lds_dst,
        16, 0, 0);
}

// tanh via fast exp; offsets only shift sample coords, error negligible.
__device__ __forceinline__ float fast_tanh(float v) {
    float t = __expf(2.0f * v);
    return 1.0f - 2.0f / (t + 1.0f);
}

// Reflection over [-0.5, size-0.5] then clip. Drift |ix - w| <= 1.503 =>
// xr < 2*size, one fold suffices.
__device__ __forceinline__ float reflect_fast(float coord, float span) {
    float xr = fabsf(coord + 0.5f);
    float out = (xr < span) ? (xr - 0.5f) : (2.0f * span - xr - 0.5f);
    return fminf(fmaxf(out, 0.0f), span - 1.0f);
}

// ================= offset kernel (v10: v7 structure + global_load_lds staging) =================
// LDS layout is linear: slot idx -> byte idx*16 (row stride 72 fl = 18 slots),
// exactly gload_lds's wave-uniform-base + lane*16 pattern. OOB granules are
// whole 16B slots -> their global src points at ZERO_TILE. Removes the
// reg->LDS round trip (~40 VALU + 4 ds_write/pair) and the mid-iteration
// vmcnt stall; the barrier drain (covered by the conv) is the only wait.
#define K1R 18
#define K1S 72
#define K1_SLOTS (K1R * 18)      // 324 16B slots per plane

__global__ __launch_bounds__(256) void offset_kernel(
        const float* __restrict__ x,
        const float* __restrict__ ow,
        const float* __restrict__ ob,
        float2* __restrict__ ws) {
    __shared__ float xs[2][2][K1R * K1S];   // [buf][ch-in-pair] = 20736 B

    const int tid = threadIdx.x;
    const int b_ = blockIdx.z;
    const int h0 = blockIdx.y * 16;
    const int w0 = blockIdx.x * 64;
    const float* xb = x + (size_t)b_ * C * HW;

    // channel-invariant per-lane staging descriptors
    int  soff[2];
    bool sok[2];
    #pragma unroll
    for (int k = 0; k < 2; ++k) {
        int idx = tid + k * 256;
        int row = idx / 18, k4 = idx - row * 18;
        int grow = h0 - 1 + row;
        int gcol = w0 - 4 + k4 * 4;
        sok[k] = (idx < K1_SLOTS) && grow >= 0 && grow < H && gcol >= 0 && (gcol + 3) < W;
        soff[k] = max(grow, 0) * W + max(gcol, 0);
    }
    const int wbase0 = (tid >> 6) * 256;          // float offset of wave's pass-0 base
    const int wbase1 = 1024 + (tid >> 6) * 256;   // pass-1 base (waves 0,1 only)

    // issue one pair's staging: 2 channels x (pass0 all waves; pass1 tid<68)
#define K1_STAGE(bufi, p) do {                                           \
        const float* xA_ = xb + (size_t)(2 * (p)) * HW;                  \
        const float* xB_ = xA_ + HW;                                     \
        gl_lds16(sok[0] ? (xA_ + soff[0]) : ZERO_TILE, &xs[bufi][0][wbase0]); \
        gl_lds16(sok[0] ? (xB_ + soff[0]) : ZERO_TILE, &xs[bufi][1][wbase0]); \
        if (tid < 68) {                                                  \
            gl_lds16(sok[1] ? (xA_ + soff[1]) : ZERO_TILE, &xs[bufi][0][wbase1]); \
            gl_lds16(sok[1] ? (xB_ + soff[1]) : ZERO_TILE, &xs[bufi][1][wbase1]); \
        }                                                                \
    } while (0)

    const int tx4 = (tid & 15) * 4;
    const int ty  = tid >> 4;

    float acc0[4], acc1[4];
    {
        float b0 = ob[0], b1 = ob[1];
        #pragma unroll
        for (int q = 0; q < 4; ++q) { acc0[q] = b0; acc1[q] = b1; }
    }

#define K1_CONV(bufp, wf0, wf1) do {                                     \
        _Pragma("unroll")                                                \
        for (int ky = 0; ky < 3; ++ky) {                                 \
            int base = (ty + ky) * K1S + tx4;                            \
            f4 A = *(const f4*)&(bufp)[base];                            \
            f4 Bv = *(const f4*)&(bufp)[base + 4];                       \
            float Cv = (bufp)[base + 8];                                 \
            float in[6] = {A.w, Bv.x, Bv.y, Bv.z, Bv.w, Cv};             \
            _Pragma("unroll")                                            \
            for (int q = 0; q < 4; ++q) {                                \
                acc0[q] = fmaf(in[q], wf0[ky*3+0], fmaf(in[q+1], wf0[ky*3+1], fmaf(in[q+2], wf0[ky*3+2], acc0[q]))); \
                acc1[q] = fmaf(in[q], wf1[ky*3+0], fmaf(in[q+1], wf1[ky*3+1], fmaf(in[q+2], wf1[ky*3+2], acc1[q]))); \
            }                                                            \
        }                                                                \
    } while (0)

    K1_STAGE(0, 0);
    __syncthreads();   // drain: pair 0 in LDS

    for (int p = 0; p < 16; ++p) {
        // async-stage pair p+1 into the other buffer (its readers finished
        // before the barrier that ended iter p-1)
        if (p + 1 < 16) K1_STAGE((p + 1) & 1, p + 1);

        const int ca = 2 * p, cb = 2 * p + 1;
        const float* wa0p = ow + ca * 9;
        const float* wa1p = ow + (C + ca) * 9;
        const float* wb0p = ow + cb * 9;
        const float* wb1p = ow + (C + cb) * 9;
        float wa0[9], wa1[9], wb0[9], wb1[9];
        #pragma unroll
        for (int k = 0; k < 9; ++k) {
            wa0[k] = wa0p[k]; wa1[k] = wa1p[k];
            wb0[k] = wb0p[k]; wb1[k] = wb1p[k];
        }

        K1_CONV(xs[p & 1][0], wa0, wa1);
        K1_CONV(xs[p & 1][1], wb0, wb1);

        __syncthreads();   // drain: pair p+1 landed; all reads of buf p done
    }

    const float sx = (float)W / (float)(W - 1);
    const float sy = (float)H / (float)(H - 1);
    const int hh = h0 + ty;
    float ixr[4], iyr[4];
    #pragma unroll
    for (int q = 0; q < 4; ++q) {
        float fx = (float)(w0 + tx4 + q) + fast_tanh(acc0[q]);
        float fy = (float)hh + fast_tanh(acc1[q]);
        ixr[q] = reflect_fast(fx * sx - 0.5f, (float)W);
        iyr[q] = reflect_fast(fy * sy - 0.5f, (float)H);
    }
    f4* p = (f4*)(ws + (size_t)b_ * HW + (size_t)hh * W + (w0 + tx4));
    f4 o0 = {ixr[0], iyr[0], ixr[1], iyr[1]};
    f4 o1 = {ixr[2], iyr[2], ixr[3], iyr[3]};
    p[0] = o0;
    p[1] = o1;
}

// ================= sample + depthwise conv (v10: unchanged from R11, passing) =================
#define NC 8
#define XT_ROWS 22
#define XT_STRIDE 72
#define XT_N (XT_ROWS * XT_STRIDE)          // 1584 floats
#define XT_LOADS (XT_ROWS * 18)             // 396 float4 loads
#define XD_ROWS 18
#define XD_COLS 66
#define XD_STRIDE 68
#define META_N (XD_ROWS * XD_COLS)          // 1188
#define K2_GX 6
#define K2_GY 24
#define K2_GZ (B * (C / NC))                // 32
#define K2_NWG (K2_GX * K2_GY * K2_GZ)      // 4608
#define K2_CPX (K2_NWG / 8)                 // 576

__global__ __launch_bounds__(256) void sample_dw_kernel(
        const float* __restrict__ x,
        const float2* __restrict__ ws,
        const float* __restrict__ dww,
        float* __restrict__ out) {
    __shared__ float xt[XT_N];
    __shared__ float xd[XD_ROWS * XD_STRIDE];
    __shared__ unsigned int m_addr[META_N];
    __shared__ float m_wx[META_N];
    __shared__ float m_wy[META_N];

    const int tid = threadIdx.x;
    // XCD-chunked bijective swizzle of the flat workgroup id
    const int id = blockIdx.x;
    const int nid = (id & 7) * K2_CPX + (id >> 3);
    const int bz = nid / (K2_GX * K2_GY);
    const int rem = nid - bz * (K2_GX * K2_GY);
    const int by = rem / K2_GX;
    const int bx = rem - by * K2_GX;

    const int b_ = bz >> 2;
    const int c0 = (bz & 3) * NC;
    const int h0 = by * 16;
    const int w0 = bx * 64;

    const float* xb = x + ((size_t)b_ * C + c0) * HW;
    const float2* wsb = ws + (size_t)b_ * HW;

    // prefetch channel 0 x-tile into regs
    f4 pf[2];
    #pragma unroll
    for (int k = 0; k < 2; ++k) {
        int idx = tid + k * 256;
        f4 v = (f4)0.0f;
        if (idx < XT_LOADS) {
            int row = idx / 18, k4 = idx % 18;
            int grow = min(max(h0 - 3 + row, 0), H - 1);
            int gcol = min(max(w0 - 4 + k4 * 4, 0), W - 4);
            v = *(const f4*)(xb + grow * W + gcol);
        }
        pf[k] = v;
    }

    // Phase A: per-pixel meta, shared across channels
    const int addr_base = (h0 - 3) * XT_STRIDE + (w0 - 4);
    #pragma unroll
    for (int k = 0; k < 5; ++k) {
        int i = tid + k * 256;
        if (i < META_N) {
            int r = i / XD_COLS, q = i - r * XD_COLS;
            int hp = h0 - 1 + r, wp = w0 - 1 + q;
            unsigned int addr = 0xFFFFFFFFu;
            float wx1 = 0.f, wy1 = 0.f;
            if (hp >= 0 && hp < H && wp >= 0 && wp < W) {
                float2 crd = wsb[hp * W + wp];
                float ix0f = floorf(crd.x), iy0f = floorf(crd.y);
                wx1 = crd.x - ix0f; wy1 = crd.y - iy0f;
                int ix0 = min(max((int)ix0f, 0), W - 1);
                int iy0 = min(max((int)iy0f, 0), H - 1);
                addr = (unsigned int)(iy0 * XT_STRIDE + ix0 - addr_base);
            }
            m_addr[i] = addr;
            m_wx[i] = wx1;
            m_wy[i] = wy1;
        }
    }
    __syncthreads();

    for (int cc = 0; cc < NC; ++cc) {
        // write staged x-tile regs -> LDS
        #pragma unroll
        for (int k = 0; k < 2; ++k) {
            int idx = tid + k * 256;
            if (idx < XT_LOADS) {
                int row = idx / 18, k4 = idx % 18;
                *(f4*)&xt[row * XT_STRIDE + k4 * 4] = pf[k];
            }
        }
        __syncthreads();

        // prefetch next channel (hides under sample+conv)
        if (cc + 1 < NC) {
            const float* xc = xb + (size_t)(cc + 1) * HW;
            #pragma unroll
            for (int k = 0; k < 2; ++k) {
                int idx = tid + k * 256;
                f4 v = (f4)0.0f;
                if (idx < XT_LOADS) {
                    int row = idx / 18, k4 = idx % 18;
                    int grow = min(max(h0 - 3 + row, 0), H - 1);
                    int gcol = min(max(w0 - 4 + k4 * 4, 0), W - 4);
                    v = *(const f4*)(xc + grow * W + gcol);
                }
                pf[k] = v;
            }
        }

        // sample from xt -> xd
        #pragma unroll
        for (int k = 0; k < 5; ++k) {
            int i = tid + k * 256;
            if (i < META_N) {
                int r = i / XD_COLS, q = i - r * XD_COLS;
                unsigned int addr = m_addr[i];
                float v = 0.0f;
                if (addr != 0xFFFFFFFFu) {
                    float wx1 = m_wx[i], wy1 = m_wy[i];
                    float wx0 = 1.0f - wx1, wy0 = 1.0f - wy1;
                    float v00 = xt[addr];
                    float v01 = xt[addr + 1];
                    float v10 = xt[addr + XT_STRIDE];
                    float v11 = xt[addr + XT_STRIDE + 1];
                    v = (v00 * wx0 + v01 * wx1) * wy0 + (v10 * wx0 + v11 * wx1) * wy1;
                }
                xd[r * XD_STRIDE + q] = v;
            }
        }

        // depthwise weights (wave-uniform -> scalar loads)
        float wk[9];
        const float* wc = dww + (size_t)(c0 + cc) * 9;
        #pragma unroll
        for (int i = 0; i < 9; ++i) wk[i] = wc[i];

        __syncthreads();

        // 3x3 depthwise conv from xd + ReLU; 2x2 outputs per thread
        const int tx2 = (tid & 31) * 2;
        const int ty0 = (tid >> 5) * 2;
        float a[2][2] = {{0.f, 0.f}, {0.f, 0.f}};
        #pragma unroll
        for (int r = 0; r < 4; ++r) {
            const float* rowp = xd + (ty0 + r) * XD_STRIDE + tx2;
            f2 p0 = *(const f2*)rowp;
            f2 p1 = *(const f2*)(rowp + 2);
            #pragma unroll
            for (int ky = 0; ky < 3; ++ky) {
                int j = r - ky;
                if (j < 0 || j > 1) continue;
                a[j][0] = fmaf(p0.x, wk[ky*3+0], fmaf(p0.y, wk[ky*3+1], fmaf(p1.x, wk[ky*3+2], a[j][0])));
                a[j][1] = fmaf(p0.y, wk[ky*3+0], fmaf(p1.x, wk[ky*3+1], fmaf(p1.y, wk[ky*3+2], a[j][1])));
            }
        }
        float* outc = out + ((size_t)b_ * C + c0 + cc) * HW;
        #pragma unroll
        for (int j = 0; j < 2; ++j) {
            f2 res;
            res.x = fmaxf(a[j][0], 0.0f);
            res.y = fmaxf(a[j][1], 0.0f);
            __builtin_nontemporal_store(res,
                (f2*)&outc[(size_t)(h0 + ty0 + j) * W + (w0 + tx2)]);
        }
        __syncthreads();
    }
}

extern "C" void kernel_launch(void* const* d_in, const int* in_sizes, int n_in,
                              void* d_out, int out_size, void* d_ws, size_t ws_size,
                              hipStream_t stream) {
    const float* x   = (const float*)d_in[0];
    const float* ow  = (const float*)d_in[1];
    const float* ob  = (const float*)d_in[2];
    const float* dww = (const float*)d_in[3];
    float* out = (float*)d_out;
    float2* ws = (float2*)d_ws;

    dim3 g1(W / 64, H / 16, B);
    offset_kernel<<<g1, 256, 0, stream>>>(x, ow, ob, ws);

    sample_dw_kernel<<<dim3(K2_NWG), 256, 0, stream>>>(x, ws, dww, out);
}

// Round 14
// 95.229 us; speedup vs baseline: 1.7996x; 1.1558x over previous
//
#include <hip/hip_runtime.h>
#include <math.h>

#define B 8
#define C 32
#define H 384
#define W 384
#define HW (H*W)

typedef float f4 __attribute__((ext_vector_type(4)));
typedef float f2 __attribute__((ext_vector_type(2)));
typedef unsigned int u4 __attribute__((ext_vector_type(4)));

// 16B of guaranteed zeros in global memory (.bss, never written) — the
// global-source target for out-of-image staging granules of gload_lds.
__device__ __attribute__((aligned(16))) float ZERO_TILE[4];

__device__ __forceinline__ void gl_lds16(const float* gsrc, float* lds_dst) {
    __builtin_amdgcn_global_load_lds(
        (const __attribute__((address_space(1))) void*)gsrc,
        (__attribute__((address_space(3))) void*)lds_dst,
        16, 0, 0);
}

// tanh via fast exp; offsets only shift sample coords, error negligible.
__device__ __forceinline__ float fast_tanh(float v) {
    float t = __expf(2.0f * v);
    return 1.0f - 2.0f / (t + 1.0f);
}

// Reflection over [-0.5, size-0.5] then clip. Drift |ix - w| <= 1.503 =>
// xr < 2*size, one fold suffices.
__device__ __forceinline__ float reflect_fast(float coord, float span) {
    float xr = fabsf(coord + 0.5f);
    float out = (xr < span) ? (xr - 0.5f) : (2.0f * span - xr - 0.5f);
    return fminf(fmaxf(out, 0.0f), span - 1.0f);
}

// Coord packing: delta from own pixel, range (-2,2), scale 2^14 -> u16.
// Decode u*2^-14 - 2 is exact fp; integer deltas (clip cases) round-trip
// bit-exactly, so the floor()-crossing hazard at coord 0 cannot occur.
#define INV_SCALE 6.103515625e-5f   // 2^-14

// ================= offset kernel (v11: v10 + packed coords + XCD swizzle) =================
#define K1R 18
#define K1S 72
#define K1_SLOTS (K1R * 18)      // 324 16B slots per plane
#define K1_NWG 1152
#define K1_CPX (K1_NWG / 8)      // 144 = one batch per XCD chunk

__global__ __launch_bounds__(256) void offset_kernel(
        const float* __restrict__ x,
        const float* __restrict__ ow,
        const float* __restrict__ ob,
        unsigned int* __restrict__ ws) {
    __shared__ float xs[2][2][K1R * K1S];   // [buf][ch-in-pair] = 20736 B

    const int tid = threadIdx.x;
    // XCD-chunked bijective swizzle (chunk = 144 = exactly one batch)
    const int id = blockIdx.x;
    const int nid = (id & 7) * K1_CPX + (id >> 3);
    const int b_ = nid / 144;
    const int rem = nid - b_ * 144;
    const int by = rem / 6;
    const int bx = rem - by * 6;
    const int h0 = by * 16;
    const int w0 = bx * 64;
    const float* xb = x + (size_t)b_ * C * HW;

    // channel-invariant per-lane staging descriptors
    int  soff[2];
    bool sok[2];
    #pragma unroll
    for (int k = 0; k < 2; ++k) {
        int idx = tid + k * 256;
        int row = idx / 18, k4 = idx - row * 18;
        int grow = h0 - 1 + row;
        int gcol = w0 - 4 + k4 * 4;
        sok[k] = (idx < K1_SLOTS) && grow >= 0 && grow < H && gcol >= 0 && (gcol + 3) < W;
        soff[k] = max(grow, 0) * W + max(gcol, 0);
    }
    const int wbase0 = (tid >> 6) * 256;          // float offset of wave's pass-0 base
    const int wbase1 = 1024 + (tid >> 6) * 256;   // pass-1 base (waves 0,1 only)

#define K1_STAGE(bufi, p) do {                                           \
        const float* xA_ = xb + (size_t)(2 * (p)) * HW;                  \
        const float* xB_ = xA_ + HW;                                     \
        gl_lds16(sok[0] ? (xA_ + soff[0]) : ZERO_TILE, &xs[bufi][0][wbase0]); \
        gl_lds16(sok[0] ? (xB_ + soff[0]) : ZERO_TILE, &xs[bufi][1][wbase0]); \
        if (tid < 68) {                                                  \
            gl_lds16(sok[1] ? (xA_ + soff[1]) : ZERO_TILE, &xs[bufi][0][wbase1]); \
            gl_lds16(sok[1] ? (xB_ + soff[1]) : ZERO_TILE, &xs[bufi][1][wbase1]); \
        }                                                                \
    } while (0)

    const int tx4 = (tid & 15) * 4;
    const int ty  = tid >> 4;

    float acc0[4], acc1[4];
    {
        float b0 = ob[0], b1 = ob[1];
        #pragma unroll
        for (int q = 0; q < 4; ++q) { acc0[q] = b0; acc1[q] = b1; }
    }

#define K1_CONV(bufp, wf0, wf1) do {                                     \
        _Pragma("unroll")                                                \
        for (int ky = 0; ky < 3; ++ky) {                                 \
            int base = (ty + ky) * K1S + tx4;                            \
            f4 A = *(const f4*)&(bufp)[base];                            \
            f4 Bv = *(const f4*)&(bufp)[base + 4];                       \
            float Cv = (bufp)[base + 8];                                 \
            float in[6] = {A.w, Bv.x, Bv.y, Bv.z, Bv.w, Cv};             \
            _Pragma("unroll")                                            \
            for (int q = 0; q < 4; ++q) {                                \
                acc0[q] = fmaf(in[q], wf0[ky*3+0], fmaf(in[q+1], wf0[ky*3+1], fmaf(in[q+2], wf0[ky*3+2], acc0[q]))); \
                acc1[q] = fmaf(in[q], wf1[ky*3+0], fmaf(in[q+1], wf1[ky*3+1], fmaf(in[q+2], wf1[ky*3+2], acc1[q]))); \
            }                                                            \
        }                                                                \
    } while (0)

    K1_STAGE(0, 0);
    __syncthreads();   // drain: pair 0 in LDS

    for (int p = 0; p < 16; ++p) {
        if (p + 1 < 16) K1_STAGE((p + 1) & 1, p + 1);

        const int ca = 2 * p, cb = 2 * p + 1;
        const float* wa0p = ow + ca * 9;
        const float* wa1p = ow + (C + ca) * 9;
        const float* wb0p = ow + cb * 9;
        const float* wb1p = ow + (C + cb) * 9;
        float wa0[9], wa1[9], wb0[9], wb1[9];
        #pragma unroll
        for (int k = 0; k < 9; ++k) {
            wa0[k] = wa0p[k]; wa1[k] = wa1p[k];
            wb0[k] = wb0p[k]; wb1[k] = wb1p[k];
        }

        K1_CONV(xs[p & 1][0], wa0, wa1);
        K1_CONV(xs[p & 1][1], wb0, wb1);

        __syncthreads();   // drain: pair p+1 landed; all reads of buf p done
    }

    const float sx = (float)W / (float)(W - 1);
    const float sy = (float)H / (float)(H - 1);
    const int hh = h0 + ty;
    u4 pk;
    #pragma unroll
    for (int q = 0; q < 4; ++q) {
        float wwp = (float)(w0 + tx4 + q);
        float fx = wwp + fast_tanh(acc0[q]);
        float fy = (float)hh + fast_tanh(acc1[q]);
        float ixr = reflect_fast(fx * sx - 0.5f, (float)W);
        float iyr = reflect_fast(fy * sy - 0.5f, (float)H);
        unsigned int ux = (unsigned int)((ixr - wwp + 2.0f) * 16384.0f + 0.5f);
        unsigned int uy = (unsigned int)((iyr - (float)hh + 2.0f) * 16384.0f + 0.5f);
        pk[q] = ux | (uy << 16);
    }
    *(u4*)&ws[(size_t)b_ * HW + (size_t)hh * W + (w0 + tx4)] = pk;
}

// ================= sample + depthwise conv (v11: v10 + packed-coord decode) =================
#define NC 8
#define XT_ROWS 22
#define XT_STRIDE 72
#define XT_N (XT_ROWS * XT_STRIDE)          // 1584 floats
#define XT_LOADS (XT_ROWS * 18)             // 396 float4 loads
#define XD_ROWS 18
#define XD_COLS 66
#define XD_STRIDE 68
#define META_N (XD_ROWS * XD_COLS)          // 1188
#define K2_GX 6
#define K2_GY 24
#define K2_GZ (B * (C / NC))                // 32
#define K2_NWG (K2_GX * K2_GY * K2_GZ)      // 4608
#define K2_CPX (K2_NWG / 8)                 // 576

__global__ __launch_bounds__(256) void sample_dw_kernel(
        const float* __restrict__ x,
        const unsigned int* __restrict__ ws,
        const float* __restrict__ dww,
        float* __restrict__ out) {
    __shared__ float xt[XT_N];
    __shared__ float xd[XD_ROWS * XD_STRIDE];
    __shared__ unsigned int m_addr[META_N];
    __shared__ float m_wx[META_N];
    __shared__ float m_wy[META_N];

    const int tid = threadIdx.x;
    // XCD-chunked bijective swizzle of the flat workgroup id
    const int id = blockIdx.x;
    const int nid = (id & 7) * K2_CPX + (id >> 3);
    const int bz = nid / (K2_GX * K2_GY);
    const int rem = nid - bz * (K2_GX * K2_GY);
    const int by = rem / K2_GX;
    const int bx = rem - by * K2_GX;

    const int b_ = bz >> 2;
    const int c0 = (bz & 3) * NC;
    const int h0 = by * 16;
    const int w0 = bx * 64;

    const float* xb = x + ((size_t)b_ * C + c0) * HW;
    const unsigned int* wsb = ws + (size_t)b_ * HW;

    // prefetch channel 0 x-tile into regs
    f4 pf[2];
    #pragma unroll
    for (int k = 0; k < 2; ++k) {
        int idx = tid + k * 256;
        f4 v = (f4)0.0f;
        if (idx < XT_LOADS) {
            int row = idx / 18, k4 = idx % 18;
            int grow = min(max(h0 - 3 + row, 0), H - 1);
            int gcol = min(max(w0 - 4 + k4 * 4, 0), W - 4);
            v = *(const f4*)(xb + grow * W + gcol);
        }
        pf[k] = v;
    }

    // Phase A: per-pixel meta, shared across channels
    const int addr_base = (h0 - 3) * XT_STRIDE + (w0 - 4);
    #pragma unroll
    for (int k = 0; k < 5; ++k) {
        int i = tid + k * 256;
        if (i < META_N) {
            int r = i / XD_COLS, q = i - r * XD_COLS;
            int hp = h0 - 1 + r, wp = w0 - 1 + q;
            unsigned int addr = 0xFFFFFFFFu;
            float wx1 = 0.f, wy1 = 0.f;
            if (hp >= 0 && hp < H && wp >= 0 && wp < W) {
                unsigned int cu = wsb[hp * W + wp];
                float ix = (float)wp + (float)(cu & 0xFFFFu) * INV_SCALE - 2.0f;
                float iy = (float)hp + (float)(cu >> 16)     * INV_SCALE - 2.0f;
                float ix0f = floorf(ix), iy0f = floorf(iy);
                wx1 = ix - ix0f; wy1 = iy - iy0f;
                int ix0 = min(max((int)ix0f, 0), W - 1);
                int iy0 = min(max((int)iy0f, 0), H - 1);
                addr = (unsigned int)(iy0 * XT_STRIDE + ix0 - addr_base);
            }
            m_addr[i] = addr;
            m_wx[i] = wx1;
            m_wy[i] = wy1;
        }
    }
    __syncthreads();

    for (int cc = 0; cc < NC; ++cc) {
        // write staged x-tile regs -> LDS
        #pragma unroll
        for (int k = 0; k < 2; ++k) {
            int idx = tid + k * 256;
            if (idx < XT_LOADS) {
                int row = idx / 18, k4 = idx % 18;
                *(f4*)&xt[row * XT_STRIDE + k4 * 4] = pf[k];
            }
        }
        __syncthreads();

        // prefetch next channel (hides under sample+conv)
        if (cc + 1 < NC) {
            const float* xc = xb + (size_t)(cc + 1) * HW;
            #pragma unroll
            for (int k = 0; k < 2; ++k) {
                int idx = tid + k * 256;
                f4 v = (f4)0.0f;
                if (idx < XT_LOADS) {
                    int row = idx / 18, k4 = idx % 18;
                    int grow = min(max(h0 - 3 + row, 0), H - 1);
                    int gcol = min(max(w0 - 4 + k4 * 4, 0), W - 4);
                    v = *(const f4*)(xc + grow * W + gcol);
                }
                pf[k] = v;
            }
        }

        // sample from xt -> xd
        #pragma unroll
        for (int k = 0; k < 5; ++k) {
            int i = tid + k * 256;
            if (i < META_N) {
                int r = i / XD_COLS, q = i - r * XD_COLS;
                unsigned int addr = m_addr[i];
                float v = 0.0f;
                if (addr != 0xFFFFFFFFu) {
                    float wx1 = m_wx[i], wy1 = m_wy[i];
                    float wx0 = 1.0f - wx1, wy0 = 1.0f - wy1;
                    float v00 = xt[addr];
                    float v01 = xt[addr + 1];
                    float v10 = xt[addr + XT_STRIDE];
                    float v11 = xt[addr + XT_STRIDE + 1];
                    v = (v00 * wx0 + v01 * wx1) * wy0 + (v10 * wx0 + v11 * wx1) * wy1;
                }
                xd[r * XD_STRIDE + q] = v;
            }
        }

        // depthwise weights (wave-uniform -> scalar loads)
        float wk[9];
        const float* wc = dww + (size_t)(c0 + cc) * 9;
        #pragma unroll
        for (int i = 0; i < 9; ++i) wk[i] = wc[i];

        __syncthreads();

        // 3x3 depthwise conv from xd + ReLU; 2x2 outputs per thread
        const int tx2 = (tid & 31) * 2;
        const int ty0 = (tid >> 5) * 2;
        float a[2][2] = {{0.f, 0.f}, {0.f, 0.f}};
        #pragma unroll
        for (int r = 0; r < 4; ++r) {
            const float* rowp = xd + (ty0 + r) * XD_STRIDE + tx2;
            f2 p0 = *(const f2*)rowp;
            f2 p1 = *(const f2*)(rowp + 2);
            #pragma unroll
            for (int ky = 0; ky < 3; ++ky) {
                int j = r - ky;
                if (j < 0 || j > 1) continue;
                a[j][0] = fmaf(p0.x, wk[ky*3+0], fmaf(p0.y, wk[ky*3+1], fmaf(p1.x, wk[ky*3+2], a[j][0])));
                a[j][1] = fmaf(p0.y, wk[ky*3+0], fmaf(p1.x, wk[ky*3+1], fmaf(p1.y, wk[ky*3+2], a[j][1])));
            }
        }
        float* outc = out + ((size_t)b_ * C + c0 + cc) * HW;
        #pragma unroll
        for (int j = 0; j < 2; ++j) {
            f2 res;
            res.x = fmaxf(a[j][0], 0.0f);
            res.y = fmaxf(a[j][1], 0.0f);
            __builtin_nontemporal_store(res,
                (f2*)&outc[(size_t)(h0 + ty0 + j) * W + (w0 + tx2)]);
        }
        __syncthreads();
    }
}

extern "C" void kernel_launch(void* const* d_in, const int* in_sizes, int n_in,
                              void* d_out, int out_size, void* d_ws, size_t ws_size,
                              hipStream_t stream) {
    const float* x   = (const float*)d_in[0];
    const float* ow  = (const float*)d_in[1];
    const float* ob  = (const float*)d_in[2];
    const float* dww = (const float*)d_in[3];
    float* out = (float*)d_out;
    unsigned int* ws = (unsigned int*)d_ws;

    offset_kernel<<<dim3(K1_NWG), 256, 0, stream>>>(x, ow, ob, ws);
    sample_dw_kernel<<<dim3(K2_NWG), 256, 0, stream>>>(x, ws, dww, out);
}